// Round 7
// baseline (323.714 us; speedup 1.0000x reference)
//
#include <hip/hip_runtime.h>
#include <hip/hip_bf16.h>

// Problem constants
#define BB_   8
#define DIM_  512
#define LIN_  4096
#define LOUT_ 8192

typedef __attribute__((ext_vector_type(8))) __bf16 bf16x8;
typedef __attribute__((ext_vector_type(4))) float  f32x4;
typedef __attribute__((ext_vector_type(8))) unsigned short u16x8;

__device__ __forceinline__ float bf2f(unsigned short u) {
  union { unsigned int i; float f; } x;
  x.i = ((unsigned int)u) << 16;
  return x.f;
}

// RNE float->bf16
__device__ __forceinline__ unsigned short f2bf(float f) {
  unsigned int u = __float_as_uint(f);
  return (unsigned short)((u + 0x7fffu + ((u >> 16) & 1u)) >> 16);
}

// async global->LDS, 16B per lane; LDS dest = wave-uniform base + lane*16
__device__ __forceinline__ void gload16(const void* g, void* l) {
  __builtin_amdgcn_global_load_lds(
      (__attribute__((address_space(1))) void*)(g),
      (__attribute__((address_space(3))) void*)(l), 16, 0, 0);
}

// ---------------------------------------------------------------------------
// 1) k_prep — heterogeneous grid, 4416 blocks (unchanged):
//    [0,192):    Mst[kk*512+e][i] = sum_d proj_w[e,d]*conv_w[d,i,kk]  (bf16)
//    [192,320):  Pcb[e] = sum_d proj_w[e,d]*conv_b[d]
//    [320,4416): Xbt[b][l][d] = bf16(x[b][d][l])
__global__ __launch_bounds__(256) void k_prep(const float* __restrict__ proj_w,
                                              const float* __restrict__ conv_w,
                                              const float* __restrict__ conv_b,
                                              const float* __restrict__ x,
                                              unsigned short* __restrict__ Mst,
                                              float* __restrict__ Pcb,
                                              unsigned short* __restrict__ Xbt) {
  __shared__ __align__(16) float sm[4160];
  const int bx  = blockIdx.x;
  const int tid = threadIdx.x;

  if (bx < 192) {
    float* Pt = sm;           // [16][68]
    float* Wt = sm + 1088;    // [16][68]
    const int kk = bx >> 6;
    const int t6 = bx & 63;
    const int et = (t6 >> 3) << 6;
    const int it = (t6 & 7) << 6;
    const int tx = tid & 15, ty = tid >> 4;
    const int le = tid & 63, lg = tid >> 6;
    float acc[4][4] = {};
    for (int d0 = 0; d0 < DIM_; d0 += 16) {
      {
        const float4 v = *(const float4*)&proj_w[(size_t)(et + le) * DIM_ + d0 + lg * 4];
        Pt[(lg * 4 + 0) * 68 + le] = v.x;
        Pt[(lg * 4 + 1) * 68 + le] = v.y;
        Pt[(lg * 4 + 2) * 68 + le] = v.z;
        Pt[(lg * 4 + 3) * 68 + le] = v.w;
      }
#pragma unroll
      for (int r = 0; r < 4; ++r) {
        const int dl = r * 4 + lg;
        Wt[dl * 68 + le] = conv_w[(size_t)(d0 + dl) * (DIM_ * 3) + (it + le) * 3 + kk];
      }
      __syncthreads();
#pragma unroll
      for (int dl = 0; dl < 16; ++dl) {
        const float4 pv = *(const float4*)&Pt[dl * 68 + ty * 4];
        const float4 wv = *(const float4*)&Wt[dl * 68 + tx * 4];
        const float pa[4] = {pv.x, pv.y, pv.z, pv.w};
        const float wa[4] = {wv.x, wv.y, wv.z, wv.w};
#pragma unroll
        for (int a = 0; a < 4; ++a)
#pragma unroll
          for (int b = 0; b < 4; ++b) acc[a][b] += pa[a] * wa[b];
      }
      __syncthreads();
    }
#pragma unroll
    for (int a = 0; a < 4; ++a) {
      uint2 pk;
      pk.x = (unsigned int)f2bf(acc[a][0]) | ((unsigned int)f2bf(acc[a][1]) << 16);
      pk.y = (unsigned int)f2bf(acc[a][2]) | ((unsigned int)f2bf(acc[a][3]) << 16);
      *(uint2*)&Mst[(size_t)(kk * DIM_ + et + ty * 4 + a) * DIM_ + it + tx * 4] = pk;
    }
  } else if (bx < 320) {
    const int idx = bx - 192;
    const int e = idx * 4 + (tid >> 6);
    const int j = tid & 63;
    float s = 0.f;
#pragma unroll
    for (int d = j; d < DIM_; d += 64) s += proj_w[(size_t)e * DIM_ + d] * conv_b[d];
#pragma unroll
    for (int off = 32; off > 0; off >>= 1) s += __shfl_down(s, off, 64);
    if (j == 0) Pcb[e] = s;
  } else {
    const int bc = bx - 320;
    const int bb = bc >> 9;
    const int dt = ((bc >> 6) & 7) << 6;
    const int lt = (bc & 63) << 6;
    const int lr  = tid >> 4;
    const int lc4 = (tid & 15) << 2;
#pragma unroll
    for (int r = 0; r < 4; ++r) {
      const int d = r * 16 + lr;
      const float4 v = *(const float4*)&x[((size_t)(bb * DIM_ + dt + d) << 12) + lt + lc4];
      float* row = sm + d * 65 + lc4;
      row[0] = v.x; row[1] = v.y; row[2] = v.z; row[3] = v.w;
    }
    __syncthreads();
#pragma unroll
    for (int rr = 0; rr < 2; ++rr) {
      const int flat = rr * 256 + tid;
      const int l  = flat >> 3;
      const int d8 = (flat & 7) << 3;
      unsigned int w[4];
#pragma unroll
      for (int p = 0; p < 4; ++p) {
        const float f0 = sm[(d8 + 2 * p + 0) * 65 + l];
        const float f1 = sm[(d8 + 2 * p + 1) * 65 + l];
        w[p] = (unsigned int)f2bf(f0) | ((unsigned int)f2bf(f1) << 16);
      }
      uint4 pk; pk.x = w[0]; pk.y = w[1]; pk.z = w[2]; pk.w = w[3];
      *(uint4*)&Xbt[((size_t)(bb * LIN_ + lt + l) << 9) + dt + d8] = pk;
    }
  }
}

// ---------------------------------------------------------------------------
// 2) k_fused — GEMM + AA filter + both biases, out written directly.
//    Per block: M=192 (3 kk x 64 e), N_out=256 (N_comp=288 with 16-col halo
//    each side), K=512, BK=32 -> 16 bodies.  8 waves 4M x 2N, wave tile
//    48x144 = 3x9 frags, 27 MFMA/body.
//    ROUND-7: single-phase body, prefetch depth P=3 (the one variable).
//    Body kt: { ds_read 12xb128 of buf[kt] | STAGE(kt+3) | lgkmcnt(0) |
//               sched_barrier | setprio1 | 27 MFMA | setprio0 | vmcnt(8) |
//               s_barrier }.
//    Per-wave FIFO (4 gloads/body incl dummies): outstanding at the wait =
//    {kt+1,kt+2,kt+3}x4 = 12 -> vmcnt(8) retires exactly buf[kt+1]; barrier
//    makes all waves' retirement visible before body kt+1's reads.  Two
//    bodies (~1300+ cyc) of latency cover vs P=2's one body (~600).
//    WAR: STAGE(kt+3) overwrites slot (kt-1)&3; all waves' reads of it
//    completed before the previous barrier (lgkmcnt(0) precedes MFMAs).
//    Drain: vmcnt 8,8,...,8 (kt<=12), 4 (kt=13), 0 (kt=14), none (kt=15).
//    Epilogue: acc -> LDS U-tile [192][296] bf16 (113.6KB, unions dead ring),
//    syncthreads, 17-tap AA combine -> out fp32.  (identical to round 4/6)
__global__ __launch_bounds__(512, 1) void k_fused(const unsigned short* __restrict__ Xbt,
                                                  const unsigned short* __restrict__ Mst,
                                                  const float* __restrict__ Pcb,
                                                  const float* __restrict__ aa,
                                                  const float* __restrict__ proj_b,
                                                  float* __restrict__ out) {
  __shared__ __align__(16) char lds[131072];
  const int tid = threadIdx.x;
  const int bid = blockIdx.x;
  // XCD-bijective swizzle (1024 = 8*128); one XCD: 16 ntiles x 8 etiles.
  const int wgs   = (bid & 7) * 128 + (bid >> 3);
  const int ntile = wgs >> 3;            // 0..127
  const int etile = wgs & 7;             // 0..7
  const int bb = ntile >> 4;
  const int L0 = (ntile & 15) << 8;      // output l base (256 per tile)
  const int l0g = L0 - 16;               // first computed column
  const int e0 = etile << 6;

  const int wave = tid >> 6;
  const int lane = tid & 63;

  // ---- staging: 32 units x 1KB per slot; wave w -> units w, w+8, w+16, w+24.
  // Units 0-11: A rows m=uu*16+rl (m = kk*64+e_local, kk=uu>>2); 12-29: B rows
  // l = l0g + (uu-12)*16 + rl (clamped to [0,4095], edges masked later);
  // 30,31: dummies (mirror A units 0,1) into the 2KB pad -> every wave issues
  // exactly 4 gloads per body -> uniform per-wave vmcnt counting.
  const unsigned short* src[4];
  int ldso[4];
  {
    const int rl = lane >> 2;
    const int sl = lane & 3;
    const int ch = sl ^ ((rl >> 1) & 3);          // pre-swizzled source chunk
#pragma unroll
    for (int i = 0; i < 4; ++i) {
      const int u  = wave + 8 * i;
      const int uu = (u >= 30) ? (u - 30) : u;
      const unsigned short* p;
      if (uu < 12) {
        const int kk = uu >> 2;
        const int er = e0 + ((uu & 3) << 4) + rl;
        p = Mst + ((size_t)(kk * 512 + er) << 9);
      } else {
        int labs = l0g + (uu - 12) * 16 + rl;
        labs = labs < 0 ? 0 : (labs > 4095 ? 4095 : labs);
        p = Xbt + ((size_t)(bb * LIN_ + labs) << 9);
      }
      src[i] = p + (ch << 3);
      ldso[i] = u << 10;
    }
  }

#define STAGE_(kt_, buf_)                              \
  do {                                                 \
    char* base_ = lds + (buf_) * 32768;                \
    gload16(src[0] + (kt_) * 32, base_ + ldso[0]);     \
    gload16(src[1] + (kt_) * 32, base_ + ldso[1]);     \
    gload16(src[2] + (kt_) * 32, base_ + ldso[2]);     \
    gload16(src[3] + (kt_) * 32, base_ + ldso[3]);     \
  } while (0)

  const int wm = wave >> 1;              // 0..3 : 48-row M strip
  const int wn = wave & 1;               // 0..1 : 144-col N half
  const int lrow = lane & 15;
  const int lc   = lane >> 4;            // k-chunk 0..3
  const int asl  = lc ^ ((lrow >> 1) & 3);
  const char* A0 = lds + ((wm * 48 + lrow) * 64 + asl * 16);
  const char* B0 = lds + (12288 + (wn * 144 + lrow) * 64 + asl * 16);

  f32x4 acc[3][9] = {};

  // ---- prologue: fill bufs 0,1,2; make buf0 visible to all waves ----
  STAGE_(0, 0); STAGE_(1, 1); STAGE_(2, 2);
  asm volatile("s_waitcnt vmcnt(8)" ::: "memory");   // buf0 landed (per wave)
  __builtin_amdgcn_s_barrier();

#pragma unroll
  for (int kt = 0; kt < 16; ++kt) {
    const int bo = (kt & 3) * 32768;
    bf16x8 af[3], bfv[9];

    // ds_read buf[kt] (retired & barrier-published at end of body kt-1)
#pragma unroll
    for (int mt = 0; mt < 3; ++mt) af[mt] = *(const bf16x8*)(A0 + bo + mt * 1024);
#pragma unroll
    for (int nt = 0; nt < 9; ++nt) bfv[nt] = *(const bf16x8*)(B0 + bo + nt * 1024);

    if (kt < 13) STAGE_(kt + 3, (kt + 3) & 3);       // P=3 prefetch

    asm volatile("s_waitcnt lgkmcnt(0)" ::: "memory");
    __builtin_amdgcn_sched_barrier(0);
    __builtin_amdgcn_s_setprio(1);
#pragma unroll
    for (int mt = 0; mt < 3; ++mt)
#pragma unroll
      for (int nt = 0; nt < 9; ++nt)
        // swapped operands: D row = l (quad*4+reg), D col = m (lane&15)
        acc[mt][nt] = __builtin_amdgcn_mfma_f32_16x16x32_bf16(bfv[nt], af[mt],
                                                              acc[mt][nt], 0, 0, 0);
    __builtin_amdgcn_s_setprio(0);

    // end of body: retire buf[kt+1] for every wave, publish via barrier
    if (kt <= 12) {
      asm volatile("s_waitcnt vmcnt(8)" ::: "memory");
    } else if (kt == 13) {
      asm volatile("s_waitcnt vmcnt(4)" ::: "memory");
    } else if (kt == 14) {
      asm volatile("s_waitcnt vmcnt(0)" ::: "memory");
    }
    __builtin_amdgcn_s_barrier();
  }
#undef STAGE_

  // ---- epilogue A: acc -> LDS U-tile (bf16, stride 296; unions dead ring) ----
  // (final end-of-body barrier separates all waves' LDS reads from Ut writes)
  unsigned short* Ut = (unsigned short*)lds;
#pragma unroll
  for (int mt = 0; mt < 3; ++mt) {
    const int m = wm * 48 + mt * 16 + lrow;          // m = kk*64 + e_local
#pragma unroll
    for (int nt = 0; nt < 9; ++nt) {
      const int lcol = wn * 144 + nt * 16 + (lc << 2);
      uint2 pk;
      pk.x = (unsigned int)f2bf(acc[mt][nt][0]) | ((unsigned int)f2bf(acc[mt][nt][1]) << 16);
      pk.y = (unsigned int)f2bf(acc[mt][nt][2]) | ((unsigned int)f2bf(acc[mt][nt][3]) << 16);
      *(uint2*)&Ut[m * 296 + lcol] = pk;
    }
  }
  __syncthreads();

  // ---- epilogue B: AA combine + biases, store out ----
  // thread t: e_local = t>>3, l-chunk base = (t&7)*32 (thread owns a 256B strip)
  const int el  = tid >> 3;
  const int lt0 = (tid & 7) << 5;
  const int e   = e0 + el;
  const float pcb = Pcb[e];
  const float pb  = proj_b[e];
  float sa[17];
#pragma unroll
  for (int j = 0; j < 17; ++j) sa[j] = aa[j];
  const unsigned short* u0r = Ut + (size_t)el * 296;          // kk=0
  const unsigned short* u1r = Ut + (size_t)(64 + el) * 296;   // kk=1
  const unsigned short* u2r = Ut + (size_t)(128 + el) * 296;  // kk=2
  const bool edge = (L0 == 0) || (L0 == 3840);
  float* orow = out + (((size_t)(bb * 512 + e)) << 13) + 2 * (size_t)(L0 + lt0);

#pragma unroll
  for (int cc = 0; cc < 4; ++cc) {
    const int c0 = lt0 + 8 * cc + 12;   // Ut col of E[0]  (c = l - l0g = c0 + j)
    float E[17], O[16];
    if (!edge) {
      // interior: aligned 16B window [c0-4, c0+20) covers all needed cols
      const u16x8 e0v = *(const u16x8*)(u1r + c0 - 4);
      const u16x8 e1v = *(const u16x8*)(u1r + c0 + 4);
      const u16x8 e2v = *(const u16x8*)(u1r + c0 + 12);
      const u16x8 a0v = *(const u16x8*)(u0r + c0 - 4);
      const u16x8 a1v = *(const u16x8*)(u0r + c0 + 4);
      const u16x8 a2v = *(const u16x8*)(u0r + c0 + 12);
      const u16x8 b0v = *(const u16x8*)(u2r + c0 - 4);
      const u16x8 b1v = *(const u16x8*)(u2r + c0 + 4);
      const u16x8 b2v = *(const u16x8*)(u2r + c0 + 12);
      unsigned short ue[24], ua[24], ub[24];
#pragma unroll
      for (int j = 0; j < 8; ++j) {
        ue[j] = e0v[j]; ue[j + 8] = e1v[j]; ue[j + 16] = e2v[j];
        ua[j] = a0v[j]; ua[j + 8] = a1v[j]; ua[j + 16] = a2v[j];
        ub[j] = b0v[j]; ub[j + 8] = b1v[j]; ub[j + 16] = b2v[j];
      }
#pragma unroll
      for (int j = 0; j < 17; ++j) E[j] = bf2f(ue[4 + j]) + pcb;
#pragma unroll
      for (int j = 0; j < 16; ++j) O[j] = bf2f(ua[4 + j]) + pcb + bf2f(ub[5 + j]);
    } else {
      const int lt = L0 + lt0 + 8 * cc;
#pragma unroll
      for (int j = 0; j < 17; ++j) {
        const int l = lt - 4 + j;
        E[j] = (l >= 0 && l < 4096) ? (bf2f(u1r[c0 + j]) + pcb) : 0.f;
      }
#pragma unroll
      for (int j = 0; j < 16; ++j) {
        const int l = lt - 4 + j;
        float v = 0.f;
        if (l >= 0 && l < 4096) {
          v = bf2f(u0r[c0 + j]) + pcb;
          if (l + 1 < 4096) v += bf2f(u2r[c0 + j + 1]);
        }
        O[j] = v;
      }
    }
    float res[16];
#pragma unroll
    for (int t = 0; t < 8; ++t) {
      float se = 0.f, so = 0.f;
#pragma unroll
      for (int q = 0; q <= 8; ++q) {   // even taps
        se += sa[2 * q] * E[t + q];
        so += sa[2 * q] * O[t + q];
      }
#pragma unroll
      for (int q = 0; q < 8; ++q) {    // odd taps
        se += sa[2 * q + 1] * O[t + q];
        so += sa[2 * q + 1] * E[t + q + 1];
      }
      res[2 * t]     = se + pb;
      res[2 * t + 1] = so + pb;
    }
#pragma unroll
    for (int c2 = 0; c2 < 4; ++c2)
      *(float4*)(orow + 16 * cc + 4 * c2) = *(const float4*)&res[4 * c2];
  }
}

// ---------------------------------------------------------------------------
extern "C" void kernel_launch(void* const* d_in, const int* in_sizes, int n_in,
                              void* d_out, int out_size, void* d_ws, size_t ws_size,
                              hipStream_t stream) {
  const float* x      = (const float*)d_in[0];
  const float* conv_w = (const float*)d_in[1];
  const float* conv_b = (const float*)d_in[2];
  const float* aa     = (const float*)d_in[3];
  const float* proj_w = (const float*)d_in[4];
  const float* proj_b = (const float*)d_in[5];
  float* out = (float*)d_out;

  char* ws = (char*)d_ws;
  unsigned short* Mst = (unsigned short*)ws;              //  1,572,864 B
  float*          Pcb = (float*)(ws + 1572864);           //      2,048 B
  unsigned short* Xbt = (unsigned short*)(ws + 1574912);  // 33,554,432 B (tot 35.1MB)

  k_prep<<<dim3(4416, 1, 1), 256, 0, stream>>>(proj_w, conv_w, conv_b, x, Mst, Pcb, Xbt);
  k_fused<<<dim3(1024, 1, 1), 512, 0, stream>>>(Xbt, Mst, Pcb, aa, proj_b, out);
}